// Round 7
// baseline (310.253 us; speedup 1.0000x reference)
//
#include <hip/hip_runtime.h>

// B=2, T=2048, C=1024, H=16, hd=64. fp32 in/out; bf16 MFMA everywhere.
// ws layout (MB offsets):
//   0: qb 8 | 8: kb 8 | 16: vt 8 | 24: xb/yb 8 | 32: woutT 2 |
//   34: vb 8 (dead after transp_v) | 42: wqkvT 6 (dead after gemm_qkv) |
//   34: po 18 MiB (aliases vb+wqkvT; written by attn_p1 only) |
//   52: pm 576K | 52+640K: pl 576K         (total ~53.3 MB)
// NOTE: softmax runs in base-2 domain (q pre-scaled by 0.125*log2e in
// gemm_qkv); exp = v_exp_f32 (2^x) directly, incl. attn_p2 merge.

#define T_SEQ 2048
#define C_DIM 1024
#define NH    16
#define HD    64
#define BT    4096

typedef short bf16x8 __attribute__((ext_vector_type(8)));   // 8 bf16 (4 VGPRs)
typedef float floatx4 __attribute__((ext_vector_type(4)));  // MFMA accum

static __device__ __forceinline__ unsigned short f2bf(float f) {
    union { float f; unsigned u; } v; v.f = f;
    unsigned u = v.u;
    return (unsigned short)((u + 0x7FFFu + ((u >> 16) & 1u)) >> 16);
}
static __device__ __forceinline__ float bf2f(unsigned short u) {
    union { unsigned u; float f; } v; v.u = ((unsigned)u) << 16; return v.f;
}
// 2^x via the TRANS pipe, no log2e pre-multiply
static __device__ __forceinline__ float exp2_fast(float x) {
    float r; asm("v_exp_f32 %0, %1" : "=v"(r) : "v"(x)); return r;
}
// pack two f32 -> 2xbf16 (RNE) in one instruction
static __device__ __forceinline__ unsigned cvt_pk_bf16(float lo, float hi) {
    unsigned r; asm("v_cvt_pk_bf16_f32 %0, %1, %2" : "=v"(r) : "v"(lo), "v"(hi)); return r;
}

// async global->LDS, 16B per lane. LDS dest must be wave-uniform base + lane*16.
static __device__ __forceinline__ void gl2lds16(const void* g, void* l) {
    __builtin_amdgcn_global_load_lds(
        (const __attribute__((address_space(1))) unsigned int*)g,
        (__attribute__((address_space(3))) unsigned int*)l, 16, 0, 0);
}

// ---------------- fused prep: x->bf16, W_qkv^T->bf16, W_out^T->bf16 --------
static __device__ __forceinline__ void transpose_body(float (*tile)[65],
                                                      const float* __restrict__ W,
                                                      unsigned short* __restrict__ Wt,
                                                      int K, int N, int bx, int by) {
    const int k0 = by << 6;
    const int n0 = bx << 6;
    const int rr = threadIdx.x >> 4;
    const int cc = (threadIdx.x & 15) << 2;
#pragma unroll
    for (int i = 0; i < 4; i++) {
        int r = rr + (i << 4);
        *(float4*)&tile[r][cc] = *(const float4*)(W + (size_t)(k0 + r) * N + n0 + cc);
    }
    __syncthreads();
#pragma unroll
    for (int i = 0; i < 4; i++) {
        int nr = rr + (i << 4);
        ushort4 o;
        o.x = f2bf(tile[cc + 0][nr]);
        o.y = f2bf(tile[cc + 1][nr]);
        o.z = f2bf(tile[cc + 2][nr]);
        o.w = f2bf(tile[cc + 3][nr]);
        *(ushort4*)(Wt + (size_t)(n0 + nr) * K + k0 + cc) = o;
    }
}

__global__ __launch_bounds__(256) void prep(const float* __restrict__ x,
                                            unsigned short* __restrict__ xb,
                                            const float* __restrict__ w_qkv,
                                            unsigned short* __restrict__ wqkvT,
                                            const float* __restrict__ w_out,
                                            unsigned short* __restrict__ woutT) {
    __shared__ float tile[64][65];
    const int bx = blockIdx.x;
    if (bx < 1024) {                       // convert x (4M floats), 4 sweeps
        int i = (bx * 256 + threadIdx.x) * 4;
        const int n = BT * C_DIM;
        const int stride = 1024 * 1024;
        for (; i < n; i += stride) {
            float4 f = *(const float4*)(x + i);
            ushort4 o;
            o.x = f2bf(f.x); o.y = f2bf(f.y); o.z = f2bf(f.z); o.w = f2bf(f.w);
            *(ushort4*)(xb + i) = o;
        }
    } else if (bx < 1024 + 768) {          // w_qkv [1024][3072] -> [3072][1024]
        int b = bx - 1024;
        transpose_body(tile, w_qkv, wqkvT, 1024, 3072, b % 48, b / 48);
    } else {                               // w_out [1024][1024] -> [1024][1024]
        int b = bx - 1024 - 768;
        transpose_body(tile, w_out, woutT, 1024, 1024, b % 16, b / 16);
    }
}

// ---------------- v [bh][t][d] -> vt [bh][d][t] (LDS tile transpose) -------
__global__ __launch_bounds__(256) void transp_v(const unsigned short* __restrict__ vb,
                                                unsigned short* __restrict__ vt) {
    __shared__ unsigned short tile[64][68];
    const int t0 = blockIdx.x << 6;
    const int bh = blockIdx.y;
    const size_t base = (size_t)bh * T_SEQ * HD;
    const int r = threadIdx.x >> 3;
    const int c = (threadIdx.x & 7) << 3;
#pragma unroll
    for (int i = 0; i < 2; i++) {
        const unsigned short* src = vb + base + (size_t)(t0 + r + (i << 5)) * HD + c;
        ushort4 u0 = *(const ushort4*)src;
        ushort4 u1 = *(const ushort4*)(src + 4);
        *(ushort4*)&tile[r + (i << 5)][c] = u0;
        *(ushort4*)&tile[r + (i << 5)][c + 4] = u1;
    }
    __syncthreads();
#pragma unroll
    for (int i = 0; i < 2; i++) {
        int s = threadIdx.x + (i << 8);
        int d = s >> 3;
        int tc = (s & 7) << 3;
        ushort4 o0, o1;
        o0.x = tile[tc + 0][d]; o0.y = tile[tc + 1][d];
        o0.z = tile[tc + 2][d]; o0.w = tile[tc + 3][d];
        o1.x = tile[tc + 4][d]; o1.y = tile[tc + 5][d];
        o1.z = tile[tc + 6][d]; o1.w = tile[tc + 7][d];
        unsigned short* dst = vt + ((size_t)bh * HD + d) * T_SEQ + t0 + tc;
        *(ushort4*)dst = o0;
        *(ushort4*)(dst + 4) = o1;
    }
}

// ---------------- m97-style bf16 MFMA GEMM core, XOR-swizzled LDS ----------
#define GEMM_CORE(A_, Bt_, K_)                                                      \
    __shared__ short As[128 * 64];                                                  \
    __shared__ short Bs[128 * 64];                                                  \
    const int tid  = threadIdx.x;                                                   \
    const int lane = tid & 63, wave = tid >> 6;                                     \
    const int ln   = lane & 15, quad = lane >> 4;                                   \
    const int wm   = wave & 1,  wn   = wave >> 1;                                   \
    const int row0 = blockIdx.y << 7;                                               \
    const int col0 = blockIdx.x << 7;                                               \
    floatx4 acc[4][4];                                                              \
    _Pragma("unroll")                                                               \
    for (int i = 0; i < 4; i++)                                                     \
        _Pragma("unroll")                                                           \
        for (int j = 0; j < 4; j++) acc[i][j] = (floatx4){0.f, 0.f, 0.f, 0.f};      \
    for (int k0 = 0; k0 < K_; k0 += 64) {                                           \
        _Pragma("unroll")                                                           \
        for (int i = 0; i < 4; i++) {                                               \
            int c = (i << 8) + tid;                                                 \
            int r = c >> 3;                                                         \
            int gsrc = (c & 7) ^ (r & 7);                                           \
            gl2lds16(A_  + (size_t)(row0 + r) * K_ + k0 + (gsrc << 3), &As[c << 3]); \
            gl2lds16(Bt_ + (size_t)(col0 + r) * K_ + k0 + (gsrc << 3), &Bs[c << 3]); \
        }                                                                           \
        __syncthreads();                                                            \
        _Pragma("unroll")                                                           \
        for (int half = 0; half < 2; half++) {                                      \
            bf16x8 af[4], bfr[4];                                                   \
            _Pragma("unroll")                                                       \
            for (int t4 = 0; t4 < 4; t4++) {                                        \
                int ra = (wm << 6) + (t4 << 4) + ln;                                \
                int rb = (wn << 6) + (t4 << 4) + ln;                                \
                int g  = (half << 2) + quad;                                        \
                af[t4]  = *(bf16x8*)&As[((ra << 3) + (g ^ (ra & 7))) << 3];         \
                bfr[t4] = *(bf16x8*)&Bs[((rb << 3) + (g ^ (rb & 7))) << 3];         \
            }                                                                       \
            _Pragma("unroll")                                                       \
            for (int mt = 0; mt < 4; mt++)                                          \
                _Pragma("unroll")                                                   \
                for (int nt = 0; nt < 4; nt++)                                      \
                    acc[mt][nt] = __builtin_amdgcn_mfma_f32_16x16x32_bf16(af[mt], bfr[nt], acc[mt][nt], 0, 0, 0); \
        }                                                                           \
        __syncthreads();                                                            \
    }

// ---------------- GEMM: qkv = X @ WqkvT^T + bias -> bf16 q/k/v (coalesced) --
// q is scaled by 0.125*log2(e) so attention softmax can use 2^x directly.
__global__ __launch_bounds__(256) void gemm_qkv(const unsigned short* __restrict__ A,
                                                const unsigned short* __restrict__ Bt,
                                                const float* __restrict__ bias,
                                                unsigned short* __restrict__ qb,
                                                unsigned short* __restrict__ kb,
                                                unsigned short* __restrict__ vb) {
    GEMM_CORE(A, Bt, 1024)
    const float QSCALE = 0.125f * 1.4426950408889634f;
#pragma unroll
    for (int mt = 0; mt < 4; mt++) {
#pragma unroll
        for (int nt = 0; nt < 4; nt++) {
            int n = col0 + (wn << 6) + (nt << 4) + ln;
            int h = n / 192, r = n % 192;
            int sel = r >> 6, d = r & 63;
            float bv = bias[n];
#pragma unroll
            for (int e = 0; e < 4; e++) {
                int m = row0 + (wm << 6) + (mt << 4) + (quad << 2) + e;
                int b = m >> 11, t = m & 2047;
                float val = acc[mt][nt][e] + bv;
                size_t idx = (((size_t)(b * NH + h)) * T_SEQ + t) * HD + d;
                if (sel == 0)
                    qb[idx] = f2bf(val * QSCALE);
                else if (sel == 1)
                    kb[idx] = f2bf(val);
                else
                    vb[idx] = f2bf(val);
            }
        }
    }
}

// ---------------- GEMM: out = Y @ WoutT^T + bias, 128x64 tile (512 blocks) --
__global__ __launch_bounds__(256) void gemm_out(const unsigned short* __restrict__ A,
                                                const unsigned short* __restrict__ Bt,
                                                const float* __restrict__ bias,
                                                float* __restrict__ out) {
    const int K = 1024, N = 1024;
    __shared__ short As[128 * 64];
    __shared__ short Bs[64 * 64];
    const int tid  = threadIdx.x;
    const int lane = tid & 63, wave = tid >> 6;
    const int ln   = lane & 15, quad = lane >> 4;
    const int wm   = wave & 1,  wn   = wave >> 1;
    const int row0 = blockIdx.y << 7;
    const int col0 = blockIdx.x << 6;
    floatx4 acc[4][2];
#pragma unroll
    for (int i = 0; i < 4; i++)
#pragma unroll
        for (int j = 0; j < 2; j++) acc[i][j] = (floatx4){0.f, 0.f, 0.f, 0.f};
    for (int k0 = 0; k0 < K; k0 += 64) {
#pragma unroll
        for (int i = 0; i < 4; i++) {          // A: 1024 chunks
            int c = (i << 8) + tid;
            int r = c >> 3;
            int gsrc = (c & 7) ^ (r & 7);
            gl2lds16(A + (size_t)(row0 + r) * K + k0 + (gsrc << 3), &As[c << 3]);
        }
#pragma unroll
        for (int i = 0; i < 2; i++) {          // B: 512 chunks
            int c = (i << 8) + tid;
            int r = c >> 3;
            int gsrc = (c & 7) ^ (r & 7);
            gl2lds16(Bt + (size_t)(col0 + r) * K + k0 + (gsrc << 3), &Bs[c << 3]);
        }
        __syncthreads();
#pragma unroll
        for (int half = 0; half < 2; half++) {
            bf16x8 af[4], bfr[2];
#pragma unroll
            for (int t4 = 0; t4 < 4; t4++) {
                int ra = (wm << 6) + (t4 << 4) + ln;
                int g  = (half << 2) + quad;
                af[t4] = *(bf16x8*)&As[((ra << 3) + (g ^ (ra & 7))) << 3];
            }
#pragma unroll
            for (int t2 = 0; t2 < 2; t2++) {
                int rb = (wn << 5) + (t2 << 4) + ln;
                int g  = (half << 2) + quad;
                bfr[t2] = *(bf16x8*)&Bs[((rb << 3) + (g ^ (rb & 7))) << 3];
            }
#pragma unroll
            for (int mt = 0; mt < 4; mt++)
#pragma unroll
                for (int nt = 0; nt < 2; nt++)
                    acc[mt][nt] = __builtin_amdgcn_mfma_f32_16x16x32_bf16(af[mt], bfr[nt], acc[mt][nt], 0, 0, 0);
        }
        __syncthreads();
    }
#pragma unroll
    for (int mt = 0; mt < 4; mt++) {
#pragma unroll
        for (int nt = 0; nt < 2; nt++) {
            int n = col0 + (wn << 5) + (nt << 4) + ln;
            float bv = bias[n];
#pragma unroll
            for (int e = 0; e < 4; e++) {
                int m = row0 + (wm << 6) + (mt << 4) + (quad << 2) + e;
                out[(size_t)m * N + n] = acc[mt][nt][e] + bv;
            }
        }
    }
}

// ---------------- MFMA flash attention pass1: barrier-free waves -----------
// Same chunk geometry as r3/r6 (qt 0..31, chunks of <=8 kt-tiles). NEW:
// no K/V LDS staging, no __syncthreads — QK A-frags load direct from kb,
// PV B-frags direct from vt (both L2-resident); the only LDS is the
// wave-private P exchange (QP rows partitioned by wave). XCD-aware block
// swizzle clusters same-bh blocks per XCD (4 bh panels/XCD L2).
// Lesson log: r2 spills (minwaves 6); r3/r4 residency knobs null; r5
// QBLK=128 regressed; r6 VALU diet -2.5% only -> latency chain is the
// limiter; this round removes the chain's barrier+staging links.
__global__ __launch_bounds__(256) void attn_p1(const unsigned short* __restrict__ qb,
                                               const unsigned short* __restrict__ kb,
                                               const unsigned short* __restrict__ vt,
                                               unsigned short* __restrict__ y,
                                               unsigned short* __restrict__ po,
                                               float* __restrict__ pm,
                                               float* __restrict__ pl) {
    __shared__ short QP[64][68];
    const int tid  = threadIdx.x;
    const int w    = tid >> 6, lane = tid & 63;
    const int ln   = lane & 15, quad = lane >> 4;

    // XCD swizzle: linear id round-robins XCDs; map so XCD x gets bh = x (mod 8)
    const int L     = blockIdx.y * 80 + blockIdx.x;   // 0..2559
    const int xcd   = L & 7;
    const int slotL = L >> 3;                          // 0..319
    const int bh    = xcd + ((slotL / 80) << 3);
    const int bx    = slotL % 80;

    int qt, c;
    if (bx < 32)      { qt = 31 - bx;        c = 0; }
    else if (bx < 56) { qt = 31 - (bx - 32); c = 1; }
    else if (bx < 72) { qt = 31 - (bx - 56); c = 2; }
    else              { qt = 31 - (bx - 72); c = 3; }
    const int kt_lo = c << 3;
    const int kt_hi = (kt_lo + 7 < qt) ? (kt_lo + 7) : qt;
    const int nc    = (qt >> 3) + 1;
    const bool fin  = (nc == 1);
    const size_t base = (size_t)bh * T_SEQ * HD;
    const int q0   = qt << 6;
    const int sb   = q0 + (w << 4);
    const float NEG_INF = -__builtin_inff();

    // Q fragments straight from global
    const unsigned short* qrow = qb + base + (size_t)(q0 + (w << 4) + ln) * HD;
    bf16x8 bq0 = *(const bf16x8*)(qrow + (quad << 3));
    bf16x8 bq1 = *(const bf16x8*)(qrow + 32 + (quad << 3));

    floatx4 o[4];
#pragma unroll
    for (int nt = 0; nt < 4; nt++) o[nt] = (floatx4){0.f, 0.f, 0.f, 0.f};
    float m_prev = NEG_INF, l_run = 0.f;

    for (int kt = kt_lo; kt <= kt_hi; kt++) {
        const int k0 = kt << 6;
        const bool diag  = (kt == qt);
        const int  nlive = diag ? w : 3;

        floatx4 st[4];
        __builtin_amdgcn_s_setprio(1);
#pragma unroll
        for (int ktl = 0; ktl < 4; ktl++) {
            if (ktl <= nlive) {
                const unsigned short* krow =
                    kb + base + (size_t)(k0 + (ktl << 4) + ln) * HD + (quad << 3);
                bf16x8 a0 = *(const bf16x8*)krow;
                bf16x8 a1 = *(const bf16x8*)(krow + 32);
                floatx4 acc = (floatx4){0.f, 0.f, 0.f, 0.f};
                acc = __builtin_amdgcn_mfma_f32_16x16x32_bf16(a0, bq0, acc, 0, 0, 0);
                acc = __builtin_amdgcn_mfma_f32_16x16x32_bf16(a1, bq1, acc, 0, 0, 0);
                st[ktl] = acc;
            }
        }
        __builtin_amdgcn_s_setprio(0);
        if (diag) {
#pragma unroll
            for (int ktl = 0; ktl < 4; ktl++) {
                if (ktl <= nlive) {
#pragma unroll
                    for (int e = 0; e < 4; e++) {
                        int kg = k0 + (ktl << 4) + (quad << 2) + e;
                        if (kg > sb + ln) st[ktl][e] = NEG_INF;
                    }
                }
            }
        }

        float mx = NEG_INF;
#pragma unroll
        for (int ktl = 0; ktl < 4; ktl++)
            if (ktl <= nlive) {
                mx = fmaxf(mx, fmaxf(fmaxf(st[ktl][0], st[ktl][1]),
                                     fmaxf(st[ktl][2], st[ktl][3])));
            }
        mx = fmaxf(mx, __shfl_xor(mx, 16));
        mx = fmaxf(mx, __shfl_xor(mx, 32));
        const bool need = __any(mx > m_prev);
        const float m_new = fmaxf(m_prev, mx);
        float psum = 0.f;
#pragma unroll
        for (int ktl = 0; ktl < 4; ktl++)
            if (ktl <= nlive) {
#pragma unroll
                for (int e = 0; e < 4; e++) {
                    float p = exp2_fast(st[ktl][e] - m_new);   // base-2 domain
                    st[ktl][e] = p;
                    psum += p;
                }
            }
        psum += __shfl_xor(psum, 16);
        psum += __shfl_xor(psum, 32);

#pragma unroll
        for (int ktl = 0; ktl < 4; ktl++) {
            uint2 pw;
            if (ktl <= nlive) {
                pw.x = cvt_pk_bf16(st[ktl][0], st[ktl][1]);
                pw.y = cvt_pk_bf16(st[ktl][2], st[ktl][3]);
            } else {
                pw.x = 0; pw.y = 0;
            }
            *(uint2*)&QP[(w << 4) + ln][(ktl << 4) + (quad << 2)] = pw;
        }

        if (need) {                       // rescale only when max grew
            float alpha = exp2_fast(m_prev - m_new);
            float arow[4];
#pragma unroll
            for (int e = 0; e < 4; e++) arow[e] = __shfl(alpha, (quad << 2) + e);
#pragma unroll
            for (int nt = 0; nt < 4; nt++)
#pragma unroll
                for (int e = 0; e < 4; e++) o[nt][e] *= arow[e];
            l_run = l_run * alpha + psum;
            m_prev = m_new;
        } else {
            l_run += psum;
        }

        bf16x8 ap0 = *(bf16x8*)&QP[(w << 4) + ln][quad << 3];
        bf16x8 ap1 = *(bf16x8*)&QP[(w << 4) + ln][32 + (quad << 3)];
        __builtin_amdgcn_s_setprio(1);
#pragma unroll
        for (int nt = 0; nt < 4; nt++) {
            const unsigned short* vrow =
                vt + base + (size_t)((nt << 4) + ln) * T_SEQ + k0 + (quad << 3);
            bf16x8 v0 = *(const bf16x8*)vrow;
            bf16x8 v1 = *(const bf16x8*)(vrow + 32);
            o[nt] = __builtin_amdgcn_mfma_f32_16x16x32_bf16(ap0, v0, o[nt], 0, 0, 0);
            o[nt] = __builtin_amdgcn_mfma_f32_16x16x32_bf16(ap1, v1, o[nt], 0, 0, 0);
        }
        __builtin_amdgcn_s_setprio(0);
    }

    if (fin) {
        // final epilogue: y[b, t, h*64+d] bf16
        float linv[4];
#pragma unroll
        for (int e = 0; e < 4; e++) linv[e] = 1.0f / __shfl(l_run, (quad << 2) + e);
        const int b = bh >> 4, h = bh & 15;
#pragma unroll
        for (int e = 0; e < 4; e++) {
            int t = sb + (quad << 2) + e;
            unsigned short* yrow = y + ((size_t)b * T_SEQ + t) * C_DIM + h * HD;
#pragma unroll
            for (int nt = 0; nt < 4; nt++)
                yrow[(nt << 4) + ln] = f2bf(o[nt][e] * linv[e]);
        }
    } else {
        // partial epilogue: unnormalized o (bf16) + m,l (fp32, base-2 m)
        int cb;
        if (qt < 16)      cb = (qt - 8) * 2;
        else if (qt < 24) cb = 16 + (qt - 16) * 3;
        else              cb = 40 + (qt - 24) * 4;
        const int slot = bh * 72 + cb + c;                 // 0..2303
        if (quad == 0) {
            pm[(slot << 6) + (w << 4) + ln] = m_prev;
            pl[(slot << 6) + (w << 4) + ln] = l_run;
        }
#pragma unroll
        for (int e = 0; e < 4; e++) {
            int q = (w << 4) + (quad << 2) + e;
            unsigned short* porow = po + (((size_t)slot << 6) + q) * HD;
#pragma unroll
            for (int nt = 0; nt < 4; nt++)
                porow[(nt << 4) + ln] = f2bf(o[nt][e]);
        }
    }
}

// ---------------- attn pass2: merge 2..4 chunks for qt>=8 (base-2 m) -------
__global__ __launch_bounds__(256) void attn_p2(const unsigned short* __restrict__ po,
                                               const float* __restrict__ pm,
                                               const float* __restrict__ pl,
                                               unsigned short* __restrict__ y) {
    const int qt = 8 + blockIdx.x;            // 8..31
    const int bh = blockIdx.y;
    const int nc = (qt >> 3) + 1;             // 2..4
    int cb;
    if (qt < 16)      cb = (qt - 8) * 2;
    else if (qt < 24) cb = 16 + (qt - 16) * 3;
    else              cb = 40 + (qt - 24) * 4;
    const int slot0 = bh * 72 + cb;
    const int tid = threadIdx.x;
    const int q  = tid >> 2;
    const int d0 = (tid & 3) << 4;
    const float NEG_INF = -__builtin_inff();

    float mv[4], lv[4];
#pragma unroll
    for (int cc = 0; cc < 4; cc++) {
        if (cc < nc) {
            mv[cc] = pm[((slot0 + cc) << 6) + q];
            lv[cc] = pl[((slot0 + cc) << 6) + q];
        } else {
            mv[cc] = NEG_INF; lv[cc] = 0.f;
        }
    }
    float m = fmaxf(fmaxf(mv[0], mv[1]), fmaxf(mv[2], mv[3]));
    float a[4];
    float L = 0.f;
#pragma unroll
    for (int cc = 0; cc < 4; cc++) {
        a[cc] = (cc < nc) ? exp2_fast(mv[cc] - m) : 0.f;
        L += lv[cc] * a[cc];
    }
    const float inv = 1.0f / L;
#pragma unroll
    for (int cc = 0; cc < 4; cc++) a[cc] *= inv;

    float acc[16];
#pragma unroll
    for (int i = 0; i < 16; i++) acc[i] = 0.f;
#pragma unroll
    for (int cc = 0; cc < 4; cc++) {
        if (cc < nc) {
            const unsigned short* r = po + (((size_t)(slot0 + cc)) << 12) + (q << 6) + d0;
            const float ac = a[cc];
#pragma unroll
            for (int i = 0; i < 4; i++) {
                ushort4 u = *(const ushort4*)(r + (i << 2));
                acc[(i << 2) + 0] += ac * bf2f(u.x);
                acc[(i << 2) + 1] += ac * bf2f(u.y);
                acc[(i << 2) + 2] += ac * bf2f(u.z);
                acc[(i << 2) + 3] += ac * bf2f(u.w);
            }
        }
    }

    const int b = bh >> 4, h = bh & 15;
    const int t = (qt << 6) + q;
    unsigned short* yrow = y + ((size_t)b * T_SEQ + t) * C_DIM + h * HD + d0;
#pragma unroll
    for (int i = 0; i < 4; i++) {
        ushort4 ow;
        ow.x = f2bf(acc[(i << 2) + 0]);
        ow.y = f2bf(acc[(i << 2) + 1]);
        ow.z = f2bf(acc[(i << 2) + 2]);
        ow.w = f2bf(acc[(i << 2) + 3]);
        *(ushort4*)(yrow + (i << 2)) = ow;
    }
}

extern "C" void kernel_launch(void* const* d_in, const int* in_sizes, int n_in,
                              void* d_out, int out_size, void* d_ws, size_t ws_size,
                              hipStream_t stream) {
    (void)in_sizes; (void)n_in; (void)out_size; (void)ws_size;
    const float* x     = (const float*)d_in[0];
    const float* w_qkv = (const float*)d_in[1];
    const float* b_qkv = (const float*)d_in[2];
    const float* w_out = (const float*)d_in[3];
    const float* b_out = (const float*)d_in[4];
    float* out = (float*)d_out;

    char* ws = (char*)d_ws;
    unsigned short* qb    = (unsigned short*)ws;                        // 8 MB
    unsigned short* kb    = (unsigned short*)(ws + ((size_t)8  << 20)); // 8 MB
    unsigned short* vt    = (unsigned short*)(ws + ((size_t)16 << 20)); // 8 MB
    unsigned short* xb    = (unsigned short*)(ws + ((size_t)24 << 20)); // 8 MB (alias yb)
    unsigned short* yb    = xb;
    unsigned short* woutT = (unsigned short*)(ws + ((size_t)32 << 20)); // 2 MB
    unsigned short* vb    = (unsigned short*)(ws + ((size_t)34 << 20)); // 8 MB (dead after transp_v)
    unsigned short* wqkvT = (unsigned short*)(ws + ((size_t)42 << 20)); // 6 MB (dead after gemm_qkv)
    unsigned short* po    = (unsigned short*)(ws + ((size_t)34 << 20)); // 18 MB, aliases vb+wqkvT
    float*          pm    = (float*)(ws + ((size_t)52 << 20));          // 576 KB
    float*          pl    = (float*)(ws + ((size_t)52 << 20) + (640 << 10)); // 576 KB

    prep    <<<2048, 256, 0, stream>>>(x, xb, w_qkv, wqkvT, w_out, woutT);
    gemm_qkv<<<dim3(24, 32), 256, 0, stream>>>(xb, wqkvT, b_qkv, qb, kb, vb);
    transp_v<<<dim3(32, 32), 256, 0, stream>>>(vb, vt);
    attn_p1 <<<dim3(80, 32), 256, 0, stream>>>(qb, kb, vt, yb, po, pm, pl);
    attn_p2 <<<dim3(24, 32), 256, 0, stream>>>(po, pm, pl, yb);
    gemm_out<<<dim3(16, 32), 256, 0, stream>>>(yb, woutT, b_out, out);
}

// Round 8
// 212.164 us; speedup vs baseline: 1.4623x; 1.4623x over previous
//
#include <hip/hip_runtime.h>

// B=2, T=2048, C=1024, H=16, hd=64. fp32 in/out; bf16 MFMA everywhere.
// ws layout (MB offsets):
//   0: qb 8 | 8: kb 8 | 16: vt 8 | 24: xb/yb 8 | 32: woutT 2 |
//   34: vb 8 (dead after transp_v) | 42: wqkvT 6 (dead after gemm_qkv) |
//   34: po 18 MiB (aliases vb+wqkvT; written by attn_p1 only) |
//   52: pm 576K | 52+640K: pl 576K         (total ~53.3 MB)
// NOTE: softmax runs in base-2 domain (q pre-scaled by 0.125*log2e in
// gemm_qkv); exp = v_exp_f32 (2^x) directly, incl. attn_p2 merge.

#define T_SEQ 2048
#define C_DIM 1024
#define NH    16
#define HD    64
#define BT    4096

typedef short bf16x8 __attribute__((ext_vector_type(8)));   // 8 bf16 (4 VGPRs)
typedef float floatx4 __attribute__((ext_vector_type(4)));  // MFMA accum

static __device__ __forceinline__ unsigned short f2bf(float f) {
    union { float f; unsigned u; } v; v.f = f;
    unsigned u = v.u;
    return (unsigned short)((u + 0x7FFFu + ((u >> 16) & 1u)) >> 16);
}
static __device__ __forceinline__ float bf2f(unsigned short u) {
    union { unsigned u; float f; } v; v.u = ((unsigned)u) << 16; return v.f;
}
// 2^x via the TRANS pipe, no log2e pre-multiply
static __device__ __forceinline__ float exp2_fast(float x) {
    float r; asm("v_exp_f32 %0, %1" : "=v"(r) : "v"(x)); return r;
}
// pack two f32 -> 2xbf16 (RNE) in one instruction
static __device__ __forceinline__ unsigned cvt_pk_bf16(float lo, float hi) {
    unsigned r; asm("v_cvt_pk_bf16_f32 %0, %1, %2" : "=v"(r) : "v"(lo), "v"(hi)); return r;
}

// async global->LDS, 16B per lane. LDS dest must be wave-uniform base + lane*16.
static __device__ __forceinline__ void gl2lds16(const void* g, void* l) {
    __builtin_amdgcn_global_load_lds(
        (const __attribute__((address_space(1))) unsigned int*)g,
        (__attribute__((address_space(3))) unsigned int*)l, 16, 0, 0);
}

// ---------------- fused prep: x->bf16, W_qkv^T->bf16, W_out^T->bf16 --------
static __device__ __forceinline__ void transpose_body(float (*tile)[65],
                                                      const float* __restrict__ W,
                                                      unsigned short* __restrict__ Wt,
                                                      int K, int N, int bx, int by) {
    const int k0 = by << 6;
    const int n0 = bx << 6;
    const int rr = threadIdx.x >> 4;
    const int cc = (threadIdx.x & 15) << 2;
#pragma unroll
    for (int i = 0; i < 4; i++) {
        int r = rr + (i << 4);
        *(float4*)&tile[r][cc] = *(const float4*)(W + (size_t)(k0 + r) * N + n0 + cc);
    }
    __syncthreads();
#pragma unroll
    for (int i = 0; i < 4; i++) {
        int nr = rr + (i << 4);
        ushort4 o;
        o.x = f2bf(tile[cc + 0][nr]);
        o.y = f2bf(tile[cc + 1][nr]);
        o.z = f2bf(tile[cc + 2][nr]);
        o.w = f2bf(tile[cc + 3][nr]);
        *(ushort4*)(Wt + (size_t)(n0 + nr) * K + k0 + cc) = o;
    }
}

__global__ __launch_bounds__(256) void prep(const float* __restrict__ x,
                                            unsigned short* __restrict__ xb,
                                            const float* __restrict__ w_qkv,
                                            unsigned short* __restrict__ wqkvT,
                                            const float* __restrict__ w_out,
                                            unsigned short* __restrict__ woutT) {
    __shared__ float tile[64][65];
    const int bx = blockIdx.x;
    if (bx < 1024) {                       // convert x (4M floats), 4 sweeps
        int i = (bx * 256 + threadIdx.x) * 4;
        const int n = BT * C_DIM;
        const int stride = 1024 * 1024;
        for (; i < n; i += stride) {
            float4 f = *(const float4*)(x + i);
            ushort4 o;
            o.x = f2bf(f.x); o.y = f2bf(f.y); o.z = f2bf(f.z); o.w = f2bf(f.w);
            *(ushort4*)(xb + i) = o;
        }
    } else if (bx < 1024 + 768) {          // w_qkv [1024][3072] -> [3072][1024]
        int b = bx - 1024;
        transpose_body(tile, w_qkv, wqkvT, 1024, 3072, b % 48, b / 48);
    } else {                               // w_out [1024][1024] -> [1024][1024]
        int b = bx - 1024 - 768;
        transpose_body(tile, w_out, woutT, 1024, 1024, b % 16, b / 16);
    }
}

// ---------------- v [bh][t][d] -> vt [bh][d][t] (LDS tile transpose) -------
__global__ __launch_bounds__(256) void transp_v(const unsigned short* __restrict__ vb,
                                                unsigned short* __restrict__ vt) {
    __shared__ unsigned short tile[64][68];
    const int t0 = blockIdx.x << 6;
    const int bh = blockIdx.y;
    const size_t base = (size_t)bh * T_SEQ * HD;
    const int r = threadIdx.x >> 3;
    const int c = (threadIdx.x & 7) << 3;
#pragma unroll
    for (int i = 0; i < 2; i++) {
        const unsigned short* src = vb + base + (size_t)(t0 + r + (i << 5)) * HD + c;
        ushort4 u0 = *(const ushort4*)src;
        ushort4 u1 = *(const ushort4*)(src + 4);
        *(ushort4*)&tile[r + (i << 5)][c] = u0;
        *(ushort4*)&tile[r + (i << 5)][c + 4] = u1;
    }
    __syncthreads();
#pragma unroll
    for (int i = 0; i < 2; i++) {
        int s = threadIdx.x + (i << 8);
        int d = s >> 3;
        int tc = (s & 7) << 3;
        ushort4 o0, o1;
        o0.x = tile[tc + 0][d]; o0.y = tile[tc + 1][d];
        o0.z = tile[tc + 2][d]; o0.w = tile[tc + 3][d];
        o1.x = tile[tc + 4][d]; o1.y = tile[tc + 5][d];
        o1.z = tile[tc + 6][d]; o1.w = tile[tc + 7][d];
        unsigned short* dst = vt + ((size_t)bh * HD + d) * T_SEQ + t0 + tc;
        *(ushort4*)dst = o0;
        *(ushort4*)(dst + 4) = o1;
    }
}

// ---------------- m97-style bf16 MFMA GEMM core, XOR-swizzled LDS ----------
#define GEMM_CORE(A_, Bt_, K_)                                                      \
    __shared__ short As[128 * 64];                                                  \
    __shared__ short Bs[128 * 64];                                                  \
    const int tid  = threadIdx.x;                                                   \
    const int lane = tid & 63, wave = tid >> 6;                                     \
    const int ln   = lane & 15, quad = lane >> 4;                                   \
    const int wm   = wave & 1,  wn   = wave >> 1;                                   \
    const int row0 = blockIdx.y << 7;                                               \
    const int col0 = blockIdx.x << 7;                                               \
    floatx4 acc[4][4];                                                              \
    _Pragma("unroll")                                                               \
    for (int i = 0; i < 4; i++)                                                     \
        _Pragma("unroll")                                                           \
        for (int j = 0; j < 4; j++) acc[i][j] = (floatx4){0.f, 0.f, 0.f, 0.f};      \
    for (int k0 = 0; k0 < K_; k0 += 64) {                                           \
        _Pragma("unroll")                                                           \
        for (int i = 0; i < 4; i++) {                                               \
            int c = (i << 8) + tid;                                                 \
            int r = c >> 3;                                                         \
            int gsrc = (c & 7) ^ (r & 7);                                           \
            gl2lds16(A_  + (size_t)(row0 + r) * K_ + k0 + (gsrc << 3), &As[c << 3]); \
            gl2lds16(Bt_ + (size_t)(col0 + r) * K_ + k0 + (gsrc << 3), &Bs[c << 3]); \
        }                                                                           \
        __syncthreads();                                                            \
        _Pragma("unroll")                                                           \
        for (int half = 0; half < 2; half++) {                                      \
            bf16x8 af[4], bfr[4];                                                   \
            _Pragma("unroll")                                                       \
            for (int t4 = 0; t4 < 4; t4++) {                                        \
                int ra = (wm << 6) + (t4 << 4) + ln;                                \
                int rb = (wn << 6) + (t4 << 4) + ln;                                \
                int g  = (half << 2) + quad;                                        \
                af[t4]  = *(bf16x8*)&As[((ra << 3) + (g ^ (ra & 7))) << 3];         \
                bfr[t4] = *(bf16x8*)&Bs[((rb << 3) + (g ^ (rb & 7))) << 3];         \
            }                                                                       \
            _Pragma("unroll")                                                       \
            for (int mt = 0; mt < 4; mt++)                                          \
                _Pragma("unroll")                                                   \
                for (int nt = 0; nt < 4; nt++)                                      \
                    acc[mt][nt] = __builtin_amdgcn_mfma_f32_16x16x32_bf16(af[mt], bfr[nt], acc[mt][nt], 0, 0, 0); \
        }                                                                           \
        __syncthreads();                                                            \
    }

// ---------------- GEMM: qkv = X @ WqkvT^T + bias -> bf16 q/k/v (coalesced) --
// q is scaled by 0.125*log2(e) so attention softmax can use 2^x directly.
__global__ __launch_bounds__(256) void gemm_qkv(const unsigned short* __restrict__ A,
                                                const unsigned short* __restrict__ Bt,
                                                const float* __restrict__ bias,
                                                unsigned short* __restrict__ qb,
                                                unsigned short* __restrict__ kb,
                                                unsigned short* __restrict__ vb) {
    GEMM_CORE(A, Bt, 1024)
    const float QSCALE = 0.125f * 1.4426950408889634f;
#pragma unroll
    for (int mt = 0; mt < 4; mt++) {
#pragma unroll
        for (int nt = 0; nt < 4; nt++) {
            int n = col0 + (wn << 6) + (nt << 4) + ln;
            int h = n / 192, r = n % 192;
            int sel = r >> 6, d = r & 63;
            float bv = bias[n];
#pragma unroll
            for (int e = 0; e < 4; e++) {
                int m = row0 + (wm << 6) + (mt << 4) + (quad << 2) + e;
                int b = m >> 11, t = m & 2047;
                float val = acc[mt][nt][e] + bv;
                size_t idx = (((size_t)(b * NH + h)) * T_SEQ + t) * HD + d;
                if (sel == 0)
                    qb[idx] = f2bf(val * QSCALE);
                else if (sel == 1)
                    kb[idx] = f2bf(val);
                else
                    vb[idx] = f2bf(val);
            }
        }
    }
}

// ---------------- GEMM: out = Y @ WoutT^T + bias, 128x64 tile (512 blocks) --
__global__ __launch_bounds__(256) void gemm_out(const unsigned short* __restrict__ A,
                                                const unsigned short* __restrict__ Bt,
                                                const float* __restrict__ bias,
                                                float* __restrict__ out) {
    const int K = 1024, N = 1024;
    __shared__ short As[128 * 64];
    __shared__ short Bs[64 * 64];
    const int tid  = threadIdx.x;
    const int lane = tid & 63, wave = tid >> 6;
    const int ln   = lane & 15, quad = lane >> 4;
    const int wm   = wave & 1,  wn   = wave >> 1;
    const int row0 = blockIdx.y << 7;
    const int col0 = blockIdx.x << 6;
    floatx4 acc[4][2];
#pragma unroll
    for (int i = 0; i < 4; i++)
#pragma unroll
        for (int j = 0; j < 2; j++) acc[i][j] = (floatx4){0.f, 0.f, 0.f, 0.f};
    for (int k0 = 0; k0 < K; k0 += 64) {
#pragma unroll
        for (int i = 0; i < 4; i++) {          // A: 1024 chunks
            int c = (i << 8) + tid;
            int r = c >> 3;
            int gsrc = (c & 7) ^ (r & 7);
            gl2lds16(A + (size_t)(row0 + r) * K + k0 + (gsrc << 3), &As[c << 3]);
        }
#pragma unroll
        for (int i = 0; i < 2; i++) {          // B: 512 chunks
            int c = (i << 8) + tid;
            int r = c >> 3;
            int gsrc = (c & 7) ^ (r & 7);
            gl2lds16(Bt + (size_t)(col0 + r) * K + k0 + (gsrc << 3), &Bs[c << 3]);
        }
        __syncthreads();
#pragma unroll
        for (int half = 0; half < 2; half++) {
            bf16x8 af[4], bfr[2];
#pragma unroll
            for (int t4 = 0; t4 < 4; t4++) {
                int ra = (wm << 6) + (t4 << 4) + ln;
                int g  = (half << 2) + quad;
                af[t4] = *(bf16x8*)&As[((ra << 3) + (g ^ (ra & 7))) << 3];
            }
#pragma unroll
            for (int t2 = 0; t2 < 2; t2++) {
                int rb = (wn << 5) + (t2 << 4) + ln;
                int g  = (half << 2) + quad;
                bfr[t2] = *(bf16x8*)&Bs[((rb << 3) + (g ^ (rb & 7))) << 3];
            }
#pragma unroll
            for (int mt = 0; mt < 4; mt++)
#pragma unroll
                for (int nt = 0; nt < 2; nt++)
                    acc[mt][nt] = __builtin_amdgcn_mfma_f32_16x16x32_bf16(af[mt], bfr[nt], acc[mt][nt], 0, 0, 0);
        }
        __syncthreads();
    }
#pragma unroll
    for (int mt = 0; mt < 4; mt++) {
#pragma unroll
        for (int nt = 0; nt < 2; nt++) {
            int n = col0 + (wn << 5) + (nt << 4) + ln;
            float bv = bias[n];
#pragma unroll
            for (int e = 0; e < 4; e++) {
                int m = row0 + (wm << 6) + (mt << 4) + (quad << 2) + e;
                out[(size_t)m * N + n] = acc[mt][nt][e] + bv;
            }
        }
    }
}

// ---------------- MFMA flash attention pass1: dbuf K/V, 1 barrier/iter -----
// r6 structure + (a) double-buffered K/V LDS: per iter {barrier; issue
// next-tile loads; compute from buf[cur]; ds_write next tile to buf[cur^1]}
// — one barrier instead of two, stage-write moved to chain tail; (b) XCD
// swizzle (r7-proven: K/V panels L2-resident, FETCH 62->12MB) so staging
// loads cost ~200cy not ~900cy.
// Lesson log: r2 spills (minwaves 6); r3/r4 residency knobs null; r5
// QBLK=128 regressed; r6 VALU diet -2.5% (latency chain, not VALU count);
// r7 no-LDS direct-global 3x worse (VMEM latency can't be hidden).
__global__ __launch_bounds__(256) void attn_p1(const unsigned short* __restrict__ qb,
                                               const unsigned short* __restrict__ kb,
                                               const unsigned short* __restrict__ vt,
                                               unsigned short* __restrict__ y,
                                               unsigned short* __restrict__ po,
                                               float* __restrict__ pm,
                                               float* __restrict__ pl) {
    __shared__ short Ks[2][64][68];
    __shared__ short Vs[2][64][68];
    __shared__ short QP[64][68];
    const int tid  = threadIdx.x;
    const int w    = tid >> 6, lane = tid & 63;
    const int ln   = lane & 15, quad = lane >> 4;

    // XCD swizzle: XCD x gets bh = x (mod 8) -> 4 bh panels per XCD L2
    const int L     = blockIdx.y * 80 + blockIdx.x;   // 0..2559
    const int xcd   = L & 7;
    const int slotL = L >> 3;                          // 0..319
    const int bh    = xcd + ((slotL / 80) << 3);
    const int bx    = slotL % 80;

    int qt, c;
    if (bx < 32)      { qt = 31 - bx;        c = 0; }
    else if (bx < 56) { qt = 31 - (bx - 32); c = 1; }
    else if (bx < 72) { qt = 31 - (bx - 56); c = 2; }
    else              { qt = 31 - (bx - 72); c = 3; }
    const int kt_lo = c << 3;
    const int kt_hi = (kt_lo + 7 < qt) ? (kt_lo + 7) : qt;
    const int nc    = (qt >> 3) + 1;
    const bool fin  = (nc == 1);
    const size_t base = (size_t)bh * T_SEQ * HD;
    const int q0   = qt << 6;
    const int sb   = q0 + (w << 4);
    const float NEG_INF = -__builtin_inff();

    const int sr = tid >> 3;
    const int sc = (tid & 7) << 3;

    // Q fragments straight from global
    const unsigned short* qrow = qb + base + (size_t)(q0 + (w << 4) + ln) * HD;
    bf16x8 bq0 = *(const bf16x8*)(qrow + (quad << 3));
    bf16x8 bq1 = *(const bf16x8*)(qrow + 32 + (quad << 3));

    // prologue: load tile kt_lo and stage into buf 0
    bf16x8 kreg[2], vreg[2];
    const int kk0 = kt_lo << 6;
#pragma unroll
    for (int i = 0; i < 2; i++) {
        kreg[i] = *(const bf16x8*)(kb + base + (size_t)(kk0 + sr + (i << 5)) * HD + sc);
        vreg[i] = *(const bf16x8*)(vt + base + (size_t)(sr + (i << 5)) * T_SEQ + kk0 + sc);
    }
#pragma unroll
    for (int i = 0; i < 2; i++) {
        *(bf16x8*)&Ks[0][sr + (i << 5)][sc] = kreg[i];
        *(bf16x8*)&Vs[0][sr + (i << 5)][sc] = vreg[i];
    }
    int cur = 0;

    floatx4 o[4];
#pragma unroll
    for (int nt = 0; nt < 4; nt++) o[nt] = (floatx4){0.f, 0.f, 0.f, 0.f};
    float m_prev = NEG_INF, l_run = 0.f;

    for (int kt = kt_lo; kt <= kt_hi; kt++) {
        const int k0 = kt << 6;
        __syncthreads();                  // buf[cur] staged by all waves
        if (kt < kt_hi) {                 // issue next-tile loads early
            const int kn = k0 + 64;
#pragma unroll
            for (int i = 0; i < 2; i++) {
                kreg[i] = *(const bf16x8*)(kb + base + (size_t)(kn + sr + (i << 5)) * HD + sc);
                vreg[i] = *(const bf16x8*)(vt + base + (size_t)(sr + (i << 5)) * T_SEQ + kn + sc);
            }
        }

        const bool diag  = (kt == qt);
        const int  nlive = diag ? w : 3;

        floatx4 st[4];
        __builtin_amdgcn_s_setprio(1);
#pragma unroll
        for (int ktl = 0; ktl < 4; ktl++) {
            if (ktl <= nlive) {
                bf16x8 a0 = *(bf16x8*)&Ks[cur][(ktl << 4) + ln][quad << 3];
                bf16x8 a1 = *(bf16x8*)&Ks[cur][(ktl << 4) + ln][32 + (quad << 3)];
                floatx4 acc = (floatx4){0.f, 0.f, 0.f, 0.f};
                acc = __builtin_amdgcn_mfma_f32_16x16x32_bf16(a0, bq0, acc, 0, 0, 0);
                acc = __builtin_amdgcn_mfma_f32_16x16x32_bf16(a1, bq1, acc, 0, 0, 0);
                st[ktl] = acc;
            }
        }
        __builtin_amdgcn_s_setprio(0);
        if (diag) {
#pragma unroll
            for (int ktl = 0; ktl < 4; ktl++) {
                if (ktl <= nlive) {
#pragma unroll
                    for (int e = 0; e < 4; e++) {
                        int kg = k0 + (ktl << 4) + (quad << 2) + e;
                        if (kg > sb + ln) st[ktl][e] = NEG_INF;
                    }
                }
            }
        }

        float mx = NEG_INF;
#pragma unroll
        for (int ktl = 0; ktl < 4; ktl++)
            if (ktl <= nlive) {
                mx = fmaxf(mx, fmaxf(fmaxf(st[ktl][0], st[ktl][1]),
                                     fmaxf(st[ktl][2], st[ktl][3])));
            }
        mx = fmaxf(mx, __shfl_xor(mx, 16));
        mx = fmaxf(mx, __shfl_xor(mx, 32));
        const bool need = __any(mx > m_prev);
        const float m_new = fmaxf(m_prev, mx);
        float psum = 0.f;
#pragma unroll
        for (int ktl = 0; ktl < 4; ktl++)
            if (ktl <= nlive) {
#pragma unroll
                for (int e = 0; e < 4; e++) {
                    float p = exp2_fast(st[ktl][e] - m_new);   // base-2 domain
                    st[ktl][e] = p;
                    psum += p;
                }
            }
        psum += __shfl_xor(psum, 16);
        psum += __shfl_xor(psum, 32);

#pragma unroll
        for (int ktl = 0; ktl < 4; ktl++) {
            uint2 pw;
            if (ktl <= nlive) {
                pw.x = cvt_pk_bf16(st[ktl][0], st[ktl][1]);
                pw.y = cvt_pk_bf16(st[ktl][2], st[ktl][3]);
            } else {
                pw.x = 0; pw.y = 0;
            }
            *(uint2*)&QP[(w << 4) + ln][(ktl << 4) + (quad << 2)] = pw;
        }

        if (need) {                       // rescale only when max grew
            float alpha = exp2_fast(m_prev - m_new);
            float arow[4];
#pragma unroll
            for (int e = 0; e < 4; e++) arow[e] = __shfl(alpha, (quad << 2) + e);
#pragma unroll
            for (int nt = 0; nt < 4; nt++)
#pragma unroll
                for (int e = 0; e < 4; e++) o[nt][e] *= arow[e];
            l_run = l_run * alpha + psum;
            m_prev = m_new;
        } else {
            l_run += psum;
        }

        bf16x8 ap0 = *(bf16x8*)&QP[(w << 4) + ln][quad << 3];
        bf16x8 ap1 = *(bf16x8*)&QP[(w << 4) + ln][32 + (quad << 3)];
        __builtin_amdgcn_s_setprio(1);
#pragma unroll
        for (int nt = 0; nt < 4; nt++) {
            bf16x8 v0 = *(bf16x8*)&Vs[cur][(nt << 4) + ln][quad << 3];
            bf16x8 v1 = *(bf16x8*)&Vs[cur][(nt << 4) + ln][32 + (quad << 3)];
            o[nt] = __builtin_amdgcn_mfma_f32_16x16x32_bf16(ap0, v0, o[nt], 0, 0, 0);
            o[nt] = __builtin_amdgcn_mfma_f32_16x16x32_bf16(ap1, v1, o[nt], 0, 0, 0);
        }
        __builtin_amdgcn_s_setprio(0);

        if (kt < kt_hi) {                 // stage next tile into other buf
#pragma unroll
            for (int i = 0; i < 2; i++) {
                *(bf16x8*)&Ks[cur ^ 1][sr + (i << 5)][sc] = kreg[i];
                *(bf16x8*)&Vs[cur ^ 1][sr + (i << 5)][sc] = vreg[i];
            }
        }
        cur ^= 1;
    }

    if (fin) {
        // final epilogue: y[b, t, h*64+d] bf16
        float linv[4];
#pragma unroll
        for (int e = 0; e < 4; e++) linv[e] = 1.0f / __shfl(l_run, (quad << 2) + e);
        const int b = bh >> 4, h = bh & 15;
#pragma unroll
        for (int e = 0; e < 4; e++) {
            int t = sb + (quad << 2) + e;
            unsigned short* yrow = y + ((size_t)b * T_SEQ + t) * C_DIM + h * HD;
#pragma unroll
            for (int nt = 0; nt < 4; nt++)
                yrow[(nt << 4) + ln] = f2bf(o[nt][e] * linv[e]);
        }
    } else {
        // partial epilogue: unnormalized o (bf16) + m,l (fp32, base-2 m)
        int cb;
        if (qt < 16)      cb = (qt - 8) * 2;
        else if (qt < 24) cb = 16 + (qt - 16) * 3;
        else              cb = 40 + (qt - 24) * 4;
        const int slot = bh * 72 + cb + c;                 // 0..2303
        if (quad == 0) {
            pm[(slot << 6) + (w << 4) + ln] = m_prev;
            pl[(slot << 6) + (w << 4) + ln] = l_run;
        }
#pragma unroll
        for (int e = 0; e < 4; e++) {
            int q = (w << 4) + (quad << 2) + e;
            unsigned short* porow = po + (((size_t)slot << 6) + q) * HD;
#pragma unroll
            for (int nt = 0; nt < 4; nt++)
                porow[(nt << 4) + ln] = f2bf(o[nt][e]);
        }
    }
}

// ---------------- attn pass2: merge 2..4 chunks for qt>=8 (base-2 m) -------
__global__ __launch_bounds__(256) void attn_p2(const unsigned short* __restrict__ po,
                                               const float* __restrict__ pm,
                                               const float* __restrict__ pl,
                                               unsigned short* __restrict__ y) {
    const int qt = 8 + blockIdx.x;            // 8..31
    const int bh = blockIdx.y;
    const int nc = (qt >> 3) + 1;             // 2..4
    int cb;
    if (qt < 16)      cb = (qt - 8) * 2;
    else if (qt < 24) cb = 16 + (qt - 16) * 3;
    else              cb = 40 + (qt - 24) * 4;
    const int slot0 = bh * 72 + cb;
    const int tid = threadIdx.x;
    const int q  = tid >> 2;
    const int d0 = (tid & 3) << 4;
    const float NEG_INF = -__builtin_inff();

    float mv[4], lv[4];
#pragma unroll
    for (int cc = 0; cc < 4; cc++) {
        if (cc < nc) {
            mv[cc] = pm[((slot0 + cc) << 6) + q];
            lv[cc] = pl[((slot0 + cc) << 6) + q];
        } else {
            mv[cc] = NEG_INF; lv[cc] = 0.f;
        }
    }
    float m = fmaxf(fmaxf(mv[0], mv[1]), fmaxf(mv[2], mv[3]));
    float a[4];
    float L = 0.f;
#pragma unroll
    for (int cc = 0; cc < 4; cc++) {
        a[cc] = (cc < nc) ? exp2_fast(mv[cc] - m) : 0.f;
        L += lv[cc] * a[cc];
    }
    const float inv = 1.0f / L;
#pragma unroll
    for (int cc = 0; cc < 4; cc++) a[cc] *= inv;

    float acc[16];
#pragma unroll
    for (int i = 0; i < 16; i++) acc[i] = 0.f;
#pragma unroll
    for (int cc = 0; cc < 4; cc++) {
        if (cc < nc) {
            const unsigned short* r = po + (((size_t)(slot0 + cc)) << 12) + (q << 6) + d0;
            const float ac = a[cc];
#pragma unroll
            for (int i = 0; i < 4; i++) {
                ushort4 u = *(const ushort4*)(r + (i << 2));
                acc[(i << 2) + 0] += ac * bf2f(u.x);
                acc[(i << 2) + 1] += ac * bf2f(u.y);
                acc[(i << 2) + 2] += ac * bf2f(u.z);
                acc[(i << 2) + 3] += ac * bf2f(u.w);
            }
        }
    }

    const int b = bh >> 4, h = bh & 15;
    const int t = (qt << 6) + q;
    unsigned short* yrow = y + ((size_t)b * T_SEQ + t) * C_DIM + h * HD + d0;
#pragma unroll
    for (int i = 0; i < 4; i++) {
        ushort4 ow;
        ow.x = f2bf(acc[(i << 2) + 0]);
        ow.y = f2bf(acc[(i << 2) + 1]);
        ow.z = f2bf(acc[(i << 2) + 2]);
        ow.w = f2bf(acc[(i << 2) + 3]);
        *(ushort4*)(yrow + (i << 2)) = ow;
    }
}

extern "C" void kernel_launch(void* const* d_in, const int* in_sizes, int n_in,
                              void* d_out, int out_size, void* d_ws, size_t ws_size,
                              hipStream_t stream) {
    (void)in_sizes; (void)n_in; (void)out_size; (void)ws_size;
    const float* x     = (const float*)d_in[0];
    const float* w_qkv = (const float*)d_in[1];
    const float* b_qkv = (const float*)d_in[2];
    const float* w_out = (const float*)d_in[3];
    const float* b_out = (const float*)d_in[4];
    float* out = (float*)d_out;

    char* ws = (char*)d_ws;
    unsigned short* qb    = (unsigned short*)ws;                        // 8 MB
    unsigned short* kb    = (unsigned short*)(ws + ((size_t)8  << 20)); // 8 MB
    unsigned short* vt    = (unsigned short*)(ws + ((size_t)16 << 20)); // 8 MB
    unsigned short* xb    = (unsigned short*)(ws + ((size_t)24 << 20)); // 8 MB (alias yb)
    unsigned short* yb    = xb;
    unsigned short* woutT = (unsigned short*)(ws + ((size_t)32 << 20)); // 2 MB
    unsigned short* vb    = (unsigned short*)(ws + ((size_t)34 << 20)); // 8 MB (dead after transp_v)
    unsigned short* wqkvT = (unsigned short*)(ws + ((size_t)42 << 20)); // 6 MB (dead after gemm_qkv)
    unsigned short* po    = (unsigned short*)(ws + ((size_t)34 << 20)); // 18 MB, aliases vb+wqkvT
    float*          pm    = (float*)(ws + ((size_t)52 << 20));          // 576 KB
    float*          pl    = (float*)(ws + ((size_t)52 << 20) + (640 << 10)); // 576 KB

    prep    <<<2048, 256, 0, stream>>>(x, xb, w_qkv, wqkvT, w_out, woutT);
    gemm_qkv<<<dim3(24, 32), 256, 0, stream>>>(xb, wqkvT, b_qkv, qb, kb, vb);
    transp_v<<<dim3(32, 32), 256, 0, stream>>>(vb, vt);
    attn_p1 <<<dim3(80, 32), 256, 0, stream>>>(qb, kb, vt, yb, po, pm, pl);
    attn_p2 <<<dim3(24, 32), 256, 0, stream>>>(po, pm, pl, yb);
    gemm_out<<<dim3(16, 32), 256, 0, stream>>>(yb, woutT, b_out, out);
}

// Round 9
// 197.227 us; speedup vs baseline: 1.5731x; 1.0757x over previous
//
#include <hip/hip_runtime.h>

// B=2, T=2048, C=1024, H=16, hd=64. fp32 in/out; bf16 MFMA everywhere.
// ws layout (MB offsets):
//   0: qb 8 | 8: kb 8 | 16: vt 8 | 24: xb/yb 8 | 32: woutT 2 |
//   34: (vb region, now unused) | 42: wqkvT 6 (dead after gemm_qkv) |
//   34: po 18 MiB (aliases unused vb + wqkvT; written by attn_p1 only) |
//   52: pm 576K | 52+640K: pl 576K         (total ~53.3 MB)
// NOTE: softmax runs in base-2 domain (q pre-scaled by 0.125*log2e in
// gemm_qkv); exp = v_exp_f32 (2^x) directly, incl. attn_p2 merge.
// vt is written DIRECTLY by gemm_qkv's epilogue (transp_v kernel removed):
// per (mt,nt) the 4 accum elements are 4 consecutive t at fixed d -> ushort4.

#define T_SEQ 2048
#define C_DIM 1024
#define NH    16
#define HD    64
#define BT    4096

typedef short bf16x8 __attribute__((ext_vector_type(8)));   // 8 bf16 (4 VGPRs)
typedef float floatx4 __attribute__((ext_vector_type(4)));  // MFMA accum

static __device__ __forceinline__ unsigned short f2bf(float f) {
    union { float f; unsigned u; } v; v.f = f;
    unsigned u = v.u;
    return (unsigned short)((u + 0x7FFFu + ((u >> 16) & 1u)) >> 16);
}
static __device__ __forceinline__ float bf2f(unsigned short u) {
    union { unsigned u; float f; } v; v.u = ((unsigned)u) << 16; return v.f;
}
// 2^x via the TRANS pipe, no log2e pre-multiply
static __device__ __forceinline__ float exp2_fast(float x) {
    float r; asm("v_exp_f32 %0, %1" : "=v"(r) : "v"(x)); return r;
}
// pack two f32 -> 2xbf16 (RNE) in one instruction
static __device__ __forceinline__ unsigned cvt_pk_bf16(float lo, float hi) {
    unsigned r; asm("v_cvt_pk_bf16_f32 %0, %1, %2" : "=v"(r) : "v"(lo), "v"(hi)); return r;
}

// async global->LDS, 16B per lane. LDS dest must be wave-uniform base + lane*16.
static __device__ __forceinline__ void gl2lds16(const void* g, void* l) {
    __builtin_amdgcn_global_load_lds(
        (const __attribute__((address_space(1))) unsigned int*)g,
        (__attribute__((address_space(3))) unsigned int*)l, 16, 0, 0);
}

// ---------------- fused prep: x->bf16, W_qkv^T->bf16, W_out^T->bf16 --------
static __device__ __forceinline__ void transpose_body(float (*tile)[65],
                                                      const float* __restrict__ W,
                                                      unsigned short* __restrict__ Wt,
                                                      int K, int N, int bx, int by) {
    const int k0 = by << 6;
    const int n0 = bx << 6;
    const int rr = threadIdx.x >> 4;
    const int cc = (threadIdx.x & 15) << 2;
#pragma unroll
    for (int i = 0; i < 4; i++) {
        int r = rr + (i << 4);
        *(float4*)&tile[r][cc] = *(const float4*)(W + (size_t)(k0 + r) * N + n0 + cc);
    }
    __syncthreads();
#pragma unroll
    for (int i = 0; i < 4; i++) {
        int nr = rr + (i << 4);
        ushort4 o;
        o.x = f2bf(tile[cc + 0][nr]);
        o.y = f2bf(tile[cc + 1][nr]);
        o.z = f2bf(tile[cc + 2][nr]);
        o.w = f2bf(tile[cc + 3][nr]);
        *(ushort4*)(Wt + (size_t)(n0 + nr) * K + k0 + cc) = o;
    }
}

__global__ __launch_bounds__(256) void prep(const float* __restrict__ x,
                                            unsigned short* __restrict__ xb,
                                            const float* __restrict__ w_qkv,
                                            unsigned short* __restrict__ wqkvT,
                                            const float* __restrict__ w_out,
                                            unsigned short* __restrict__ woutT) {
    __shared__ float tile[64][65];
    const int bx = blockIdx.x;
    if (bx < 1024) {                       // convert x (4M floats), 4 sweeps
        int i = (bx * 256 + threadIdx.x) * 4;
        const int n = BT * C_DIM;
        const int stride = 1024 * 1024;
        for (; i < n; i += stride) {
            float4 f = *(const float4*)(x + i);
            ushort4 o;
            o.x = f2bf(f.x); o.y = f2bf(f.y); o.z = f2bf(f.z); o.w = f2bf(f.w);
            *(ushort4*)(xb + i) = o;
        }
    } else if (bx < 1024 + 768) {          // w_qkv [1024][3072] -> [3072][1024]
        int b = bx - 1024;
        transpose_body(tile, w_qkv, wqkvT, 1024, 3072, b % 48, b / 48);
    } else {                               // w_out [1024][1024] -> [1024][1024]
        int b = bx - 1024 - 768;
        transpose_body(tile, w_out, woutT, 1024, 1024, b % 16, b / 16);
    }
}

// ---------------- m97-style bf16 MFMA GEMM core, XOR-swizzled LDS ----------
#define GEMM_CORE(A_, Bt_, K_)                                                      \
    __shared__ short As[128 * 64];                                                  \
    __shared__ short Bs[128 * 64];                                                  \
    const int tid  = threadIdx.x;                                                   \
    const int lane = tid & 63, wave = tid >> 6;                                     \
    const int ln   = lane & 15, quad = lane >> 4;                                   \
    const int wm   = wave & 1,  wn   = wave >> 1;                                   \
    const int row0 = blockIdx.y << 7;                                               \
    const int col0 = blockIdx.x << 7;                                               \
    floatx4 acc[4][4];                                                              \
    _Pragma("unroll")                                                               \
    for (int i = 0; i < 4; i++)                                                     \
        _Pragma("unroll")                                                           \
        for (int j = 0; j < 4; j++) acc[i][j] = (floatx4){0.f, 0.f, 0.f, 0.f};      \
    for (int k0 = 0; k0 < K_; k0 += 64) {                                           \
        _Pragma("unroll")                                                           \
        for (int i = 0; i < 4; i++) {                                               \
            int c = (i << 8) + tid;                                                 \
            int r = c >> 3;                                                         \
            int gsrc = (c & 7) ^ (r & 7);                                           \
            gl2lds16(A_  + (size_t)(row0 + r) * K_ + k0 + (gsrc << 3), &As[c << 3]); \
            gl2lds16(Bt_ + (size_t)(col0 + r) * K_ + k0 + (gsrc << 3), &Bs[c << 3]); \
        }                                                                           \
        __syncthreads();                                                            \
        _Pragma("unroll")                                                           \
        for (int half = 0; half < 2; half++) {                                      \
            bf16x8 af[4], bfr[4];                                                   \
            _Pragma("unroll")                                                       \
            for (int t4 = 0; t4 < 4; t4++) {                                        \
                int ra = (wm << 6) + (t4 << 4) + ln;                                \
                int rb = (wn << 6) + (t4 << 4) + ln;                                \
                int g  = (half << 2) + quad;                                        \
                af[t4]  = *(bf16x8*)&As[((ra << 3) + (g ^ (ra & 7))) << 3];         \
                bfr[t4] = *(bf16x8*)&Bs[((rb << 3) + (g ^ (rb & 7))) << 3];         \
            }                                                                       \
            _Pragma("unroll")                                                       \
            for (int mt = 0; mt < 4; mt++)                                          \
                _Pragma("unroll")                                                   \
                for (int nt = 0; nt < 4; nt++)                                      \
                    acc[mt][nt] = __builtin_amdgcn_mfma_f32_16x16x32_bf16(af[mt], bfr[nt], acc[mt][nt], 0, 0, 0); \
        }                                                                           \
        __syncthreads();                                                            \
    }

// ---------------- GEMM: qkv = X @ WqkvT^T + bias -> bf16 q/k/vt ------------
// q is scaled by 0.125*log2(e) so attention softmax can use 2^x directly.
// v is written TRANSPOSED into vt[bh][d][t] (4 consecutive t per thread).
__global__ __launch_bounds__(256) void gemm_qkv(const unsigned short* __restrict__ A,
                                                const unsigned short* __restrict__ Bt,
                                                const float* __restrict__ bias,
                                                unsigned short* __restrict__ qb,
                                                unsigned short* __restrict__ kb,
                                                unsigned short* __restrict__ vt) {
    GEMM_CORE(A, Bt, 1024)
    const float QSCALE = 0.125f * 1.4426950408889634f;
#pragma unroll
    for (int mt = 0; mt < 4; mt++) {
#pragma unroll
        for (int nt = 0; nt < 4; nt++) {
            int n = col0 + (wn << 6) + (nt << 4) + ln;
            int h = n / 192, r = n % 192;
            int sel = r >> 6, d = r & 63;
            float bv = bias[n];
            int m0 = row0 + (wm << 6) + (mt << 4) + (quad << 2);
            int b  = m0 >> 11, t0 = m0 & 2047;       // 4 elems stay in one b
            if (sel == 2) {
                ushort4 o4;
                o4.x = f2bf(acc[mt][nt][0] + bv);
                o4.y = f2bf(acc[mt][nt][1] + bv);
                o4.z = f2bf(acc[mt][nt][2] + bv);
                o4.w = f2bf(acc[mt][nt][3] + bv);
                *(ushort4*)(vt + (((size_t)(b * NH + h)) * HD + d) * T_SEQ + t0) = o4;
            } else if (sel == 0) {
#pragma unroll
                for (int e = 0; e < 4; e++) {
                    size_t idx = (((size_t)(b * NH + h)) * T_SEQ + t0 + e) * HD + d;
                    qb[idx] = f2bf((acc[mt][nt][e] + bv) * QSCALE);
                }
            } else {
#pragma unroll
                for (int e = 0; e < 4; e++) {
                    size_t idx = (((size_t)(b * NH + h)) * T_SEQ + t0 + e) * HD + d;
                    kb[idx] = f2bf(acc[mt][nt][e] + bv);
                }
            }
        }
    }
}

// ---------------- GEMM: out = Y @ WoutT^T + bias, 128x64 tile (512 blocks) --
__global__ __launch_bounds__(256) void gemm_out(const unsigned short* __restrict__ A,
                                                const unsigned short* __restrict__ Bt,
                                                const float* __restrict__ bias,
                                                float* __restrict__ out) {
    const int K = 1024, N = 1024;
    __shared__ short As[128 * 64];
    __shared__ short Bs[64 * 64];
    const int tid  = threadIdx.x;
    const int lane = tid & 63, wave = tid >> 6;
    const int ln   = lane & 15, quad = lane >> 4;
    const int wm   = wave & 1,  wn   = wave >> 1;
    const int row0 = blockIdx.y << 7;
    const int col0 = blockIdx.x << 6;
    floatx4 acc[4][2];
#pragma unroll
    for (int i = 0; i < 4; i++)
#pragma unroll
        for (int j = 0; j < 2; j++) acc[i][j] = (floatx4){0.f, 0.f, 0.f, 0.f};
    for (int k0 = 0; k0 < K; k0 += 64) {
#pragma unroll
        for (int i = 0; i < 4; i++) {          // A: 1024 chunks
            int c = (i << 8) + tid;
            int r = c >> 3;
            int gsrc = (c & 7) ^ (r & 7);
            gl2lds16(A + (size_t)(row0 + r) * K + k0 + (gsrc << 3), &As[c << 3]);
        }
#pragma unroll
        for (int i = 0; i < 2; i++) {          // B: 512 chunks
            int c = (i << 8) + tid;
            int r = c >> 3;
            int gsrc = (c & 7) ^ (r & 7);
            gl2lds16(Bt + (size_t)(col0 + r) * K + k0 + (gsrc << 3), &Bs[c << 3]);
        }
        __syncthreads();
#pragma unroll
        for (int half = 0; half < 2; half++) {
            bf16x8 af[4], bfr[2];
#pragma unroll
            for (int t4 = 0; t4 < 4; t4++) {
                int ra = (wm << 6) + (t4 << 4) + ln;
                int g  = (half << 2) + quad;
                af[t4] = *(bf16x8*)&As[((ra << 3) + (g ^ (ra & 7))) << 3];
            }
#pragma unroll
            for (int t2 = 0; t2 < 2; t2++) {
                int rb = (wn << 5) + (t2 << 4) + ln;
                int g  = (half << 2) + quad;
                bfr[t2] = *(bf16x8*)&Bs[((rb << 3) + (g ^ (rb & 7))) << 3];
            }
#pragma unroll
            for (int mt = 0; mt < 4; mt++)
#pragma unroll
                for (int nt = 0; nt < 2; nt++)
                    acc[mt][nt] = __builtin_amdgcn_mfma_f32_16x16x32_bf16(af[mt], bfr[nt], acc[mt][nt], 0, 0, 0);
        }
        __syncthreads();
    }
#pragma unroll
    for (int mt = 0; mt < 4; mt++) {
#pragma unroll
        for (int nt = 0; nt < 2; nt++) {
            int n = col0 + (wn << 5) + (nt << 4) + ln;
            float bv = bias[n];
#pragma unroll
            for (int e = 0; e < 4; e++) {
                int m = row0 + (wm << 6) + (mt << 4) + (quad << 2) + e;
                out[(size_t)m * N + n] = acc[mt][nt][e] + bv;
            }
        }
    }
}

// ---------------- MFMA flash attention pass1: r6 structure + XCD swizzle ---
// r6 (proven 56us): 2 barriers/iter, reg-prefetch K/V, base-2 softmax,
// cvt_pk P-pack, defer-rescale, setprio. NEW: XCD swizzle only (r7/r8
// proven: FETCH 62->12MB, K/V panels L2-resident -> shorter staging leg).
// Lesson log: r2 spills (minwaves 6); r3/r4 residency knobs null; r5
// QBLK=128 regressed; r6 VALU diet -2.5%; r7 no-LDS 3x worse (VMEM latency);
// r8 dbuf single-barrier regressed (LDS 43.5KB cut residency).
__global__ __launch_bounds__(256, 4) void attn_p1(const unsigned short* __restrict__ qb,
                                                  const unsigned short* __restrict__ kb,
                                                  const unsigned short* __restrict__ vt,
                                                  unsigned short* __restrict__ y,
                                                  unsigned short* __restrict__ po,
                                                  float* __restrict__ pm,
                                                  float* __restrict__ pl) {
    __shared__ short Ks[64][68];
    __shared__ short Vs[64][68];
    __shared__ short QP[64][68];
    const int tid  = threadIdx.x;
    const int w    = tid >> 6, lane = tid & 63;
    const int ln   = lane & 15, quad = lane >> 4;

    // XCD swizzle: XCD x gets bh = x (mod 8) -> 4 bh panels per XCD L2
    const int L     = blockIdx.y * 80 + blockIdx.x;   // 0..2559
    const int xcd   = L & 7;
    const int slotL = L >> 3;                          // 0..319
    const int bh    = xcd + ((slotL / 80) << 3);
    const int bx    = slotL % 80;

    int qt, c;
    if (bx < 32)      { qt = 31 - bx;        c = 0; }
    else if (bx < 56) { qt = 31 - (bx - 32); c = 1; }
    else if (bx < 72) { qt = 31 - (bx - 56); c = 2; }
    else              { qt = 31 - (bx - 72); c = 3; }
    const int kt_lo = c << 3;
    const int kt_hi = (kt_lo + 7 < qt) ? (kt_lo + 7) : qt;
    const int nc    = (qt >> 3) + 1;
    const bool fin  = (nc == 1);
    const size_t base = (size_t)bh * T_SEQ * HD;
    const int q0   = qt << 6;
    const int sb   = q0 + (w << 4);
    const float NEG_INF = -__builtin_inff();

    const int sr = tid >> 3;
    const int sc = (tid & 7) << 3;

    // Q fragments straight from global (no LDS staging / extra barrier)
    const unsigned short* qrow = qb + base + (size_t)(q0 + (w << 4) + ln) * HD;
    bf16x8 bq0 = *(const bf16x8*)(qrow + (quad << 3));
    bf16x8 bq1 = *(const bf16x8*)(qrow + 32 + (quad << 3));

    // prefetch K/V tile kt_lo into regs
    bf16x8 kreg[2], vreg[2];
    const int kk0 = kt_lo << 6;
#pragma unroll
    for (int i = 0; i < 2; i++) {
        kreg[i] = *(const bf16x8*)(kb + base + (size_t)(kk0 + sr + (i << 5)) * HD + sc);
        vreg[i] = *(const bf16x8*)(vt + base + (size_t)(sr + (i << 5)) * T_SEQ + kk0 + sc);
    }

    floatx4 o[4];
#pragma unroll
    for (int nt = 0; nt < 4; nt++) o[nt] = (floatx4){0.f, 0.f, 0.f, 0.f};
    float m_prev = NEG_INF, l_run = 0.f;

    for (int kt = kt_lo; kt <= kt_hi; kt++) {
        const int k0 = kt << 6;
        __syncthreads();
#pragma unroll
        for (int i = 0; i < 2; i++) {
            *(bf16x8*)&Ks[sr + (i << 5)][sc] = kreg[i];
            *(bf16x8*)&Vs[sr + (i << 5)][sc] = vreg[i];
        }
        __syncthreads();
        if (kt < kt_hi) {
            const int kn = k0 + 64;
#pragma unroll
            for (int i = 0; i < 2; i++) {
                kreg[i] = *(const bf16x8*)(kb + base + (size_t)(kn + sr + (i << 5)) * HD + sc);
                vreg[i] = *(const bf16x8*)(vt + base + (size_t)(sr + (i << 5)) * T_SEQ + kn + sc);
            }
        }

        const bool diag  = (kt == qt);
        const int  nlive = diag ? w : 3;

        floatx4 st[4];
        __builtin_amdgcn_s_setprio(1);
#pragma unroll
        for (int ktl = 0; ktl < 4; ktl++) {
            if (ktl <= nlive) {
                bf16x8 a0 = *(bf16x8*)&Ks[(ktl << 4) + ln][quad << 3];
                bf16x8 a1 = *(bf16x8*)&Ks[(ktl << 4) + ln][32 + (quad << 3)];
                floatx4 acc = (floatx4){0.f, 0.f, 0.f, 0.f};
                acc = __builtin_amdgcn_mfma_f32_16x16x32_bf16(a0, bq0, acc, 0, 0, 0);
                acc = __builtin_amdgcn_mfma_f32_16x16x32_bf16(a1, bq1, acc, 0, 0, 0);
                st[ktl] = acc;
            }
        }
        __builtin_amdgcn_s_setprio(0);
        if (diag) {
#pragma unroll
            for (int ktl = 0; ktl < 4; ktl++) {
                if (ktl <= nlive) {
#pragma unroll
                    for (int e = 0; e < 4; e++) {
                        int kg = k0 + (ktl << 4) + (quad << 2) + e;
                        if (kg > sb + ln) st[ktl][e] = NEG_INF;
                    }
                }
            }
        }

        float mx = NEG_INF;
#pragma unroll
        for (int ktl = 0; ktl < 4; ktl++)
            if (ktl <= nlive) {
                mx = fmaxf(mx, fmaxf(fmaxf(st[ktl][0], st[ktl][1]),
                                     fmaxf(st[ktl][2], st[ktl][3])));
            }
        mx = fmaxf(mx, __shfl_xor(mx, 16));
        mx = fmaxf(mx, __shfl_xor(mx, 32));
        const bool need = __any(mx > m_prev);
        const float m_new = fmaxf(m_prev, mx);
        float psum = 0.f;
#pragma unroll
        for (int ktl = 0; ktl < 4; ktl++)
            if (ktl <= nlive) {
#pragma unroll
                for (int e = 0; e < 4; e++) {
                    float p = exp2_fast(st[ktl][e] - m_new);   // base-2 domain
                    st[ktl][e] = p;
                    psum += p;
                }
            }
        psum += __shfl_xor(psum, 16);
        psum += __shfl_xor(psum, 32);

#pragma unroll
        for (int ktl = 0; ktl < 4; ktl++) {
            uint2 pw;
            if (ktl <= nlive) {
                pw.x = cvt_pk_bf16(st[ktl][0], st[ktl][1]);
                pw.y = cvt_pk_bf16(st[ktl][2], st[ktl][3]);
            } else {
                pw.x = 0; pw.y = 0;
            }
            *(uint2*)&QP[(w << 4) + ln][(ktl << 4) + (quad << 2)] = pw;
        }

        if (need) {                       // rescale only when max grew
            float alpha = exp2_fast(m_prev - m_new);
            float arow[4];
#pragma unroll
            for (int e = 0; e < 4; e++) arow[e] = __shfl(alpha, (quad << 2) + e);
#pragma unroll
            for (int nt = 0; nt < 4; nt++)
#pragma unroll
                for (int e = 0; e < 4; e++) o[nt][e] *= arow[e];
            l_run = l_run * alpha + psum;
            m_prev = m_new;
        } else {
            l_run += psum;
        }

        bf16x8 ap0 = *(bf16x8*)&QP[(w << 4) + ln][quad << 3];
        bf16x8 ap1 = *(bf16x8*)&QP[(w << 4) + ln][32 + (quad << 3)];
        __builtin_amdgcn_s_setprio(1);
#pragma unroll
        for (int nt = 0; nt < 4; nt++) {
            bf16x8 v0 = *(bf16x8*)&Vs[(nt << 4) + ln][quad << 3];
            bf16x8 v1 = *(bf16x8*)&Vs[(nt << 4) + ln][32 + (quad << 3)];
            o[nt] = __builtin_amdgcn_mfma_f32_16x16x32_bf16(ap0, v0, o[nt], 0, 0, 0);
            o[nt] = __builtin_amdgcn_mfma_f32_16x16x32_bf16(ap1, v1, o[nt], 0, 0, 0);
        }
        __builtin_amdgcn_s_setprio(0);
    }

    if (fin) {
        // final epilogue: y[b, t, h*64+d] bf16
        float linv[4];
#pragma unroll
        for (int e = 0; e < 4; e++) linv[e] = 1.0f / __shfl(l_run, (quad << 2) + e);
        const int b = bh >> 4, h = bh & 15;
#pragma unroll
        for (int e = 0; e < 4; e++) {
            int t = sb + (quad << 2) + e;
            unsigned short* yrow = y + ((size_t)b * T_SEQ + t) * C_DIM + h * HD;
#pragma unroll
            for (int nt = 0; nt < 4; nt++)
                yrow[(nt << 4) + ln] = f2bf(o[nt][e] * linv[e]);
        }
    } else {
        // partial epilogue: unnormalized o (bf16) + m,l (fp32, base-2 m)
        int cb;
        if (qt < 16)      cb = (qt - 8) * 2;
        else if (qt < 24) cb = 16 + (qt - 16) * 3;
        else              cb = 40 + (qt - 24) * 4;
        const int slot = bh * 72 + cb + c;                 // 0..2303
        if (quad == 0) {
            pm[(slot << 6) + (w << 4) + ln] = m_prev;
            pl[(slot << 6) + (w << 4) + ln] = l_run;
        }
#pragma unroll
        for (int e = 0; e < 4; e++) {
            int q = (w << 4) + (quad << 2) + e;
            unsigned short* porow = po + (((size_t)slot << 6) + q) * HD;
#pragma unroll
            for (int nt = 0; nt < 4; nt++)
                porow[(nt << 4) + ln] = f2bf(o[nt][e]);
        }
    }
}

// ---------------- attn pass2: merge 2..4 chunks for qt>=8 (base-2 m) -------
__global__ __launch_bounds__(256) void attn_p2(const unsigned short* __restrict__ po,
                                               const float* __restrict__ pm,
                                               const float* __restrict__ pl,
                                               unsigned short* __restrict__ y) {
    const int qt = 8 + blockIdx.x;            // 8..31
    const int bh = blockIdx.y;
    const int nc = (qt >> 3) + 1;             // 2..4
    int cb;
    if (qt < 16)      cb = (qt - 8) * 2;
    else if (qt < 24) cb = 16 + (qt - 16) * 3;
    else              cb = 40 + (qt - 24) * 4;
    const int slot0 = bh * 72 + cb;
    const int tid = threadIdx.x;
    const int q  = tid >> 2;
    const int d0 = (tid & 3) << 4;
    const float NEG_INF = -__builtin_inff();

    float mv[4], lv[4];
#pragma unroll
    for (int cc = 0; cc < 4; cc++) {
        if (cc < nc) {
            mv[cc] = pm[((slot0 + cc) << 6) + q];
            lv[cc] = pl[((slot0 + cc) << 6) + q];
        } else {
            mv[cc] = NEG_INF; lv[cc] = 0.f;
        }
    }
    float m = fmaxf(fmaxf(mv[0], mv[1]), fmaxf(mv[2], mv[3]));
    float a[4];
    float L = 0.f;
#pragma unroll
    for (int cc = 0; cc < 4; cc++) {
        a[cc] = (cc < nc) ? exp2_fast(mv[cc] - m) : 0.f;
        L += lv[cc] * a[cc];
    }
    const float inv = 1.0f / L;
#pragma unroll
    for (int cc = 0; cc < 4; cc++) a[cc] *= inv;

    float acc[16];
#pragma unroll
    for (int i = 0; i < 16; i++) acc[i] = 0.f;
#pragma unroll
    for (int cc = 0; cc < 4; cc++) {
        if (cc < nc) {
            const unsigned short* r = po + (((size_t)(slot0 + cc)) << 12) + (q << 6) + d0;
            const float ac = a[cc];
#pragma unroll
            for (int i = 0; i < 4; i++) {
                ushort4 u = *(const ushort4*)(r + (i << 2));
                acc[(i << 2) + 0] += ac * bf2f(u.x);
                acc[(i << 2) + 1] += ac * bf2f(u.y);
                acc[(i << 2) + 2] += ac * bf2f(u.z);
                acc[(i << 2) + 3] += ac * bf2f(u.w);
            }
        }
    }

    const int b = bh >> 4, h = bh & 15;
    const int t = (qt << 6) + q;
    unsigned short* yrow = y + ((size_t)b * T_SEQ + t) * C_DIM + h * HD + d0;
#pragma unroll
    for (int i = 0; i < 4; i++) {
        ushort4 ow;
        ow.x = f2bf(acc[(i << 2) + 0]);
        ow.y = f2bf(acc[(i << 2) + 1]);
        ow.z = f2bf(acc[(i << 2) + 2]);
        ow.w = f2bf(acc[(i << 2) + 3]);
        *(ushort4*)(yrow + (i << 2)) = ow;
    }
}

extern "C" void kernel_launch(void* const* d_in, const int* in_sizes, int n_in,
                              void* d_out, int out_size, void* d_ws, size_t ws_size,
                              hipStream_t stream) {
    (void)in_sizes; (void)n_in; (void)out_size; (void)ws_size;
    const float* x     = (const float*)d_in[0];
    const float* w_qkv = (const float*)d_in[1];
    const float* b_qkv = (const float*)d_in[2];
    const float* w_out = (const float*)d_in[3];
    const float* b_out = (const float*)d_in[4];
    float* out = (float*)d_out;

    char* ws = (char*)d_ws;
    unsigned short* qb    = (unsigned short*)ws;                        // 8 MB
    unsigned short* kb    = (unsigned short*)(ws + ((size_t)8  << 20)); // 8 MB
    unsigned short* vt    = (unsigned short*)(ws + ((size_t)16 << 20)); // 8 MB
    unsigned short* xb    = (unsigned short*)(ws + ((size_t)24 << 20)); // 8 MB (alias yb)
    unsigned short* yb    = xb;
    unsigned short* woutT = (unsigned short*)(ws + ((size_t)32 << 20)); // 2 MB
    unsigned short* wqkvT = (unsigned short*)(ws + ((size_t)42 << 20)); // 6 MB (dead after gemm_qkv)
    unsigned short* po    = (unsigned short*)(ws + ((size_t)34 << 20)); // 18 MB, aliases dead region
    float*          pm    = (float*)(ws + ((size_t)52 << 20));          // 576 KB
    float*          pl    = (float*)(ws + ((size_t)52 << 20) + (640 << 10)); // 576 KB

    prep    <<<2048, 256, 0, stream>>>(x, xb, w_qkv, wqkvT, w_out, woutT);
    gemm_qkv<<<dim3(24, 32), 256, 0, stream>>>(xb, wqkvT, b_qkv, qb, kb, vt);
    attn_p1 <<<dim3(80, 32), 256, 0, stream>>>(qb, kb, vt, yb, po, pm, pl);
    attn_p2 <<<dim3(24, 32), 256, 0, stream>>>(po, pm, pl, yb);
    gemm_out<<<dim3(16, 32), 256, 0, stream>>>(yb, woutT, b_out, out);
}